// Round 1
// 243.188 us; speedup vs baseline: 1.1488x; 1.1488x over previous
//
#include <hip/hip_runtime.h>
#include <hip/hip_bf16.h>

#define Dd 2048
#define Ss 2048
#define Bb 2
#define Hh 16
#define HDd 128
#define BSs (Bb*Ss)
#define NTILES 32  // 2048 / 64

typedef __bf16 bf16;
typedef __bf16 bf16x8 __attribute__((ext_vector_type(8)));
typedef __bf16 bf16x4 __attribute__((ext_vector_type(4)));
typedef float f32x4 __attribute__((ext_vector_type(4)));

__device__ __forceinline__ void gload_lds16(const void* g, void* l) {
  __builtin_amdgcn_global_load_lds((__attribute__((address_space(1))) void*)(g),
                                   (__attribute__((address_space(3))) void*)(l), 16, 0, 0);
}

template <int N>
__device__ __forceinline__ void waitv() {
  if constexpr (N == 0) asm volatile("s_waitcnt vmcnt(0)" ::: "memory");
  else if constexpr (N == 2) asm volatile("s_waitcnt vmcnt(2)" ::: "memory");
  else if constexpr (N == 4) asm volatile("s_waitcnt vmcnt(4)" ::: "memory");
  else if constexpr (N == 6) asm volatile("s_waitcnt vmcnt(6)" ::: "memory");
  else if constexpr (N == 8) asm volatile("s_waitcnt vmcnt(8)" ::: "memory");
  else if constexpr (N == 10) asm volatile("s_waitcnt vmcnt(10)" ::: "memory");
  // N < 0: no wait
}

// ---------------- x -> bf16 ----------------
__global__ void k_cvtx(const float* __restrict__ x, bf16* __restrict__ xb) {
  int i = (blockIdx.x * 256 + threadIdx.x) * 4;
  f32x4 v = *(const f32x4*)(x + i);
  bf16x4 o;
  o[0] = (bf16)v[0]; o[1] = (bf16)v[1]; o[2] = (bf16)v[2]; o[3] = (bf16)v[3];
  *(bf16x4*)(xb + i) = o;
}

// ------------- W [K][N] fp32 -> Wt [N][K] bf16 (x4 weights), 64x64 tiles, vectorized -------------
__global__ void k_tw(const float* __restrict__ W0, const float* __restrict__ W1,
                     const float* __restrict__ W2, const float* __restrict__ W3,
                     bf16* __restrict__ T0, bf16* __restrict__ T1,
                     bf16* __restrict__ T2, bf16* __restrict__ T3) {
  const float* W; bf16* T;
  switch (blockIdx.z) {
    case 0: W = W0; T = T0; break;
    case 1: W = W1; T = T1; break;
    case 2: W = W2; T = T2; break;
    default: W = W3; T = T3; break;
  }
  __shared__ float t[64][65];
  int n0 = blockIdx.x * 64, k0 = blockIdx.y * 64;
  int tid = threadIdx.x;  // 256
#pragma unroll
  for (int rr = 0; rr < 4; rr++) {
    int r = (tid >> 4) + rr * 16;
    f32x4 vv = *(const f32x4*)(W + (size_t)(k0 + r) * Dd + n0 + (tid & 15) * 4);
#pragma unroll
    for (int j = 0; j < 4; j++) t[r][(tid & 15) * 4 + j] = vv[j];
  }
  __syncthreads();
#pragma unroll
  for (int rr = 0; rr < 4; rr++) {
    int n = rr * 16 + (tid >> 4);
    int kb = (tid & 15) * 4;
    bf16x4 o;
#pragma unroll
    for (int j = 0; j < 4; j++) o[j] = (bf16)t[kb + j][n];
    *(bf16x4*)(T + (size_t)(n0 + n) * Dd + k0 + kb) = o;
  }
}

// ------------- doc position ids (prefix-max scan per batch) -------------
__global__ void k_pos(const int* __restrict__ doc, int* __restrict__ pos) {
  int b = blockIdx.x;
  __shared__ int bp[2][Ss];
  const int* db = doc + (size_t)b * Ss;
  for (int i = threadIdx.x; i < Ss; i += 1024) {
    int bd = (i == 0) || (db[i] != db[i - 1]);
    bp[0][i] = bd ? i : 0;
  }
  __syncthreads();
  int src = 0;
  for (int off = 1; off < Ss; off <<= 1) {
    for (int i = threadIdx.x; i < Ss; i += 1024) {
      int v = bp[src][i];
      if (i >= off) v = max(v, bp[src][i - off]);
      bp[1 - src][i] = v;
    }
    __syncthreads();
    src = 1 - src;
  }
  for (int i = threadIdx.x; i < Ss; i += 1024)
    pos[(size_t)b * Ss + i] = i - bp[src][i];
}

// ================= 256x256 4-phase GEMM core (deep prefetch) =================
// (unchanged from prior version — see ledger comments)
__device__ __forceinline__ bf16x8 lds_frag(const char* buf, int row, int cb) {
  return *(const bf16x8*)(buf + row * 128 + (cb ^ ((row & 7) << 4)));
}

// slot: 0=A-up,1=B-up,2=B-lo,3=A-lo. Stages K-tile t into buf[t&1].
__device__ __forceinline__ void stage_slot(const bf16* gA, const bf16* gB,
                                           int m0, int n0, int t, int slot,
                                           char* AL, char* BL, int tid) {
  const char* gp; char* l; int rbase;
  char* bufA = AL + (size_t)((t & 1) * 32768);
  char* bufB = BL + (size_t)((t & 1) * 32768);
  if (slot == 0)      { gp = (const char*)gA; l = bufA;         rbase = m0; }
  else if (slot == 1) { gp = (const char*)gB; l = bufB;         rbase = n0; }
  else if (slot == 2) { gp = (const char*)gB; l = bufB + 16384; rbase = n0 + 128; }
  else                { gp = (const char*)gA; l = bufA + 16384; rbase = m0 + 128; }
  int ktb = t * 128;  // k-tile byte offset within a 4096 B row
#pragma unroll
  for (int p = 0; p < 2; p++) {
    int o = p * 8192 + tid * 16;
    int r = o >> 7, cb = o & 127;
    gload_lds16(gp + (size_t)(rbase + r) * 4096 + ktb + (cb ^ ((r & 7) << 4)), l + o);
  }
}

template <bool STAGE, int WV0, int WV1, int WV3>
__device__ __forceinline__ void do_tile(const bf16* gA, const bf16* gB, int m0, int n0,
                                        int t, char* AL, char* BL, int tid,
                                        int wr, int wc, int ln, int g,
                                        f32x4 acc[8][4]) {
  const char* tileA = AL + (size_t)((t & 1) * 32768);
  const char* tileB = BL + (size_t)((t & 1) * 32768);
  bf16x8 af[4][2], bfU[2][2], bfL[2][2];

  // ---- phase 0: quadrant (Mh0, Nh0); load A-up + B-up; burst-stage tile t+1 ----
#pragma unroll
  for (int mq = 0; mq < 4; mq++)
#pragma unroll
    for (int kk = 0; kk < 2; kk++)
      af[mq][kk] = lds_frag(tileA, wr * 64 + mq * 16 + ln, kk * 64 + g * 16);
#pragma unroll
  for (int nq = 0; nq < 2; nq++)
#pragma unroll
    for (int kk = 0; kk < 2; kk++)
      bfU[nq][kk] = lds_frag(tileB, wc * 32 + nq * 16 + ln, kk * 64 + g * 16);
  if (STAGE) {
    stage_slot(gA, gB, m0, n0, t + 1, 0, AL, BL, tid);
    stage_slot(gA, gB, m0, n0, t + 1, 1, AL, BL, tid);
    stage_slot(gA, gB, m0, n0, t + 1, 2, AL, BL, tid);
    stage_slot(gA, gB, m0, n0, t + 1, 3, AL, BL, tid);
  }
  waitv<WV0>();
  __builtin_amdgcn_s_barrier();
  __builtin_amdgcn_s_setprio(1);
#pragma unroll
  for (int mq = 0; mq < 4; mq++)
#pragma unroll
    for (int nq = 0; nq < 2; nq++)
#pragma unroll
      for (int kk = 0; kk < 2; kk++)
        acc[mq][nq] = __builtin_amdgcn_mfma_f32_16x16x32_bf16(af[mq][kk], bfU[nq][kk], acc[mq][nq], 0, 0, 0);
  __builtin_amdgcn_s_setprio(0);
  __builtin_amdgcn_s_barrier();

  // ---- phase 1: quadrant (Mh0, Nh1); load B-lo; reuse A-up ----
#pragma unroll
  for (int nq = 0; nq < 2; nq++)
#pragma unroll
    for (int kk = 0; kk < 2; kk++)
      bfL[nq][kk] = lds_frag(tileB, 128 + wc * 32 + nq * 16 + ln, kk * 64 + g * 16);
  waitv<WV1>();
  __builtin_amdgcn_s_barrier();
  __builtin_amdgcn_s_setprio(1);
#pragma unroll
  for (int mq = 0; mq < 4; mq++)
#pragma unroll
    for (int nq = 0; nq < 2; nq++)
#pragma unroll
      for (int kk = 0; kk < 2; kk++)
        acc[mq][2 + nq] = __builtin_amdgcn_mfma_f32_16x16x32_bf16(af[mq][kk], bfL[nq][kk], acc[mq][2 + nq], 0, 0, 0);
  __builtin_amdgcn_s_setprio(0);
  __builtin_amdgcn_s_barrier();

  // ---- phase 2: quadrant (Mh1, Nh0); load A-lo; reuse B-up (regs) ----
#pragma unroll
  for (int mq = 0; mq < 4; mq++)
#pragma unroll
    for (int kk = 0; kk < 2; kk++)
      af[mq][kk] = lds_frag(tileA, 128 + wr * 64 + mq * 16 + ln, kk * 64 + g * 16);
  __builtin_amdgcn_s_barrier();
  __builtin_amdgcn_s_setprio(1);
#pragma unroll
  for (int mq = 0; mq < 4; mq++)
#pragma unroll
    for (int nq = 0; nq < 2; nq++)
#pragma unroll
      for (int kk = 0; kk < 2; kk++)
        acc[4 + mq][nq] = __builtin_amdgcn_mfma_f32_16x16x32_bf16(af[mq][kk], bfU[nq][kk], acc[4 + mq][nq], 0, 0, 0);
  __builtin_amdgcn_s_setprio(0);
  __builtin_amdgcn_s_barrier();

  // ---- phase 3: quadrant (Mh1, Nh1); no LDS reads; reuse A-lo + B-lo ----
  waitv<WV3>();
  __builtin_amdgcn_s_barrier();
  __builtin_amdgcn_s_setprio(1);
#pragma unroll
  for (int mq = 0; mq < 4; mq++)
#pragma unroll
    for (int nq = 0; nq < 2; nq++)
#pragma unroll
      for (int kk = 0; kk < 2; kk++)
        acc[4 + mq][2 + nq] = __builtin_amdgcn_mfma_f32_16x16x32_bf16(af[mq][kk], bfL[nq][kk], acc[4 + mq][2 + nq], 0, 0, 0);
  __builtin_amdgcn_s_setprio(0);
  __builtin_amdgcn_s_barrier();
}

__device__ __forceinline__ void gemm256_core(const bf16* gA, const bf16* gB,
                                             int m0, int n0, char* AL, char* BL,
                                             f32x4 acc[8][4]) {
  const int tid = threadIdx.x;
  const int l = tid & 63, w = tid >> 6;
  const int wr = w >> 2, wc = w & 3;
  const int g = l >> 4, ln = l & 15;
  f32x4 z = {0.f, 0.f, 0.f, 0.f};
#pragma unroll
  for (int i = 0; i < 8; i++)
#pragma unroll
    for (int n = 0; n < 4; n++) acc[i][n] = z;

  stage_slot(gA, gB, m0, n0, 0, 0, AL, BL, tid);
  stage_slot(gA, gB, m0, n0, 0, 1, AL, BL, tid);
  stage_slot(gA, gB, m0, n0, 0, 2, AL, BL, tid);
  stage_slot(gA, gB, m0, n0, 0, 3, AL, BL, tid);
  waitv<4>();
  __builtin_amdgcn_s_barrier();

  for (int t = 0; t < NTILES - 1; t++)
    do_tile<true, 10, 8, 4>(gA, gB, m0, n0, t, AL, BL, tid, wr, wc, ln, g, acc);
  do_tile<false, 2, 0, -1>(gA, gB, m0, n0, NTILES - 1, AL, BL, tid, wr, wc, ln, g, acc);
}

// ================= 128x256 2-phase GEMM core (for the 4096x2048 out-proj) =================
// A [M][2048], B [N][2048]. Tile 128x256. 8 waves as 2(M) x 4(N), wave tile 64x64.
// LDS: 2 dbuf x (A [128][64]=16K + B [256][64]=32K) = 96 KiB.
// Slots: s0=A (2 loads), s1=B-up (2), s2=B-lo (2). Burst all 3 slots of t+1 at ph0 of t.
// Ledger: entry outstanding = s2(t) (2); ph0 issues 6 -> 8, vmcnt(6) retires s2(t);
//         ph1 vmcnt(2) retires s0,s1(t+1). Last tile: vmcnt(0) / no wait.
__device__ __forceinline__ void stage_slot128(const bf16* gA, const bf16* gB,
                                              int m0, int n0, int t, int slot,
                                              char* AL, char* BL, int tid) {
  const char* gp; char* l; int rbase;
  char* bufA = AL + (size_t)((t & 1) * 16384);
  char* bufB = BL + (size_t)((t & 1) * 32768);
  if (slot == 0)      { gp = (const char*)gA; l = bufA;         rbase = m0; }
  else if (slot == 1) { gp = (const char*)gB; l = bufB;         rbase = n0; }
  else                { gp = (const char*)gB; l = bufB + 16384; rbase = n0 + 128; }
  int ktb = t * 128;
#pragma unroll
  for (int p = 0; p < 2; p++) {
    int o = p * 8192 + tid * 16;
    int r = o >> 7, cb = o & 127;
    gload_lds16(gp + (size_t)(rbase + r) * 4096 + ktb + (cb ^ ((r & 7) << 4)), l + o);
  }
}

template <bool STAGE, int WV0, int WV1>
__device__ __forceinline__ void do_tile128(const bf16* gA, const bf16* gB, int m0, int n0,
                                           int t, char* AL, char* BL, int tid,
                                           int wr, int wc, int ln, int g,
                                           f32x4 acc[4][4]) {
  const char* tileA = AL + (size_t)((t & 1) * 16384);
  const char* tileB = BL + (size_t)((t & 1) * 32768);
  bf16x8 af[4][2], bf_[2][2];

  // ---- phase 0: read A + B-up of t; burst stage t+1; retire s2(t) ----
#pragma unroll
  for (int mq = 0; mq < 4; mq++)
#pragma unroll
    for (int kk = 0; kk < 2; kk++)
      af[mq][kk] = lds_frag(tileA, wr * 64 + mq * 16 + ln, kk * 64 + g * 16);
#pragma unroll
  for (int nq = 0; nq < 2; nq++)
#pragma unroll
    for (int kk = 0; kk < 2; kk++)
      bf_[nq][kk] = lds_frag(tileB, wc * 32 + nq * 16 + ln, kk * 64 + g * 16);
  if (STAGE) {
    stage_slot128(gA, gB, m0, n0, t + 1, 0, AL, BL, tid);
    stage_slot128(gA, gB, m0, n0, t + 1, 1, AL, BL, tid);
    stage_slot128(gA, gB, m0, n0, t + 1, 2, AL, BL, tid);
  }
  waitv<WV0>();
  __builtin_amdgcn_s_barrier();
  __builtin_amdgcn_s_setprio(1);
#pragma unroll
  for (int mq = 0; mq < 4; mq++)
#pragma unroll
    for (int nq = 0; nq < 2; nq++)
#pragma unroll
      for (int kk = 0; kk < 2; kk++)
        acc[mq][nq] = __builtin_amdgcn_mfma_f32_16x16x32_bf16(af[mq][kk], bf_[nq][kk], acc[mq][nq], 0, 0, 0);
  __builtin_amdgcn_s_setprio(0);
  __builtin_amdgcn_s_barrier();

  // ---- phase 1: read B-lo of t; retire s0,s1(t+1) ----
#pragma unroll
  for (int nq = 0; nq < 2; nq++)
#pragma unroll
    for (int kk = 0; kk < 2; kk++)
      bf_[nq][kk] = lds_frag(tileB, 128 + wc * 32 + nq * 16 + ln, kk * 64 + g * 16);
  waitv<WV1>();
  __builtin_amdgcn_s_barrier();
  __builtin_amdgcn_s_setprio(1);
#pragma unroll
  for (int mq = 0; mq < 4; mq++)
#pragma unroll
    for (int nq = 0; nq < 2; nq++)
#pragma unroll
      for (int kk = 0; kk < 2; kk++)
        acc[mq][2 + nq] = __builtin_amdgcn_mfma_f32_16x16x32_bf16(af[mq][kk], bf_[nq][kk], acc[mq][2 + nq], 0, 0, 0);
  __builtin_amdgcn_s_setprio(0);
  __builtin_amdgcn_s_barrier();
}

__device__ __forceinline__ void gemm128_core(const bf16* gA, const bf16* gB,
                                             int m0, int n0, char* AL, char* BL,
                                             f32x4 acc[4][4]) {
  const int tid = threadIdx.x;
  const int l = tid & 63, w = tid >> 6;
  const int wr = w >> 2, wc = w & 3;
  const int g = l >> 4, ln = l & 15;
  f32x4 z = {0.f, 0.f, 0.f, 0.f};
#pragma unroll
  for (int i = 0; i < 4; i++)
#pragma unroll
    for (int n = 0; n < 4; n++) acc[i][n] = z;

  // prologue: stage all 3 slots of tile 0; retire s0,s1 (leave s2 = 2)
  stage_slot128(gA, gB, m0, n0, 0, 0, AL, BL, tid);
  stage_slot128(gA, gB, m0, n0, 0, 1, AL, BL, tid);
  stage_slot128(gA, gB, m0, n0, 0, 2, AL, BL, tid);
  waitv<2>();
  __builtin_amdgcn_s_barrier();

  for (int t = 0; t < NTILES - 1; t++)
    do_tile128<true, 6, 2>(gA, gB, m0, n0, t, AL, BL, tid, wr, wc, ln, g, acc);
  do_tile128<false, 0, -1>(gA, gB, m0, n0, NTILES - 1, AL, BL, tid, wr, wc, ln, g, acc);
}

// ------------- fused QKV projection + RoPE epilogue -------------
// gB = wqkvt [6144][2048]; cols 0-2047 -> Q, 2048-4095 -> K, 4096-6143 -> V.
// Q,K out: [B][H][S][HD] (LDS-transpose epilogue, vectorized 16B stores, in-register RoPE pairs).
// V out: DIRECT transposed [B][H][HD][S] bf16x4 stores (r2-quad = 4 consecutive s) — k_tv removed.
__global__ __launch_bounds__(512, 2) void k_qkv256(const bf16* __restrict__ xb,
                                                   const bf16* __restrict__ wqkvt,
                                                   const int* __restrict__ pos,
                                                   bf16* __restrict__ q,
                                                   bf16* __restrict__ k,
                                                   bf16* __restrict__ vt) {
  __shared__ char SLM[133120];  // GEMM uses first 128 KiB; epilogue uses 128x260 f32 view
  char* AL = SLM;
  char* BL = SLM + 65536;
  int bid = blockIdx.x;                    // 384 blocks
  int idx = (bid & 7) * 48 + (bid >> 3);   // XCD swizzle (384 % 8 == 0)
  int mt = idx / 24, nt = idx % 24;
  int m0 = mt * 256, n0 = nt * 256;

  f32x4 acc[8][4];
  gemm256_core(xb, wqkvt, m0, n0, AL, BL, acc);

  const int tid = threadIdx.x;
  const int l = tid & 63, w = tid >> 6;
  const int wr = w >> 2, wc = w & 3, g = l >> 4, ln = l & 15;
  int z = n0 >> 11;                         // 0=Q 1=K 2=V (block-uniform)
  int n0l = n0 & 2047;
  int bix = m0 >> 11;
  int sl0 = m0 & 2047;

  if (z == 2) {
    // V: straight from acc, transposed layout [B][H][HD][S], 8 B stores
#pragma unroll
    for (int mi = 0; mi < 8; mi++) {
      int sl = sl0 + (mi >> 2) * 128 + wr * 64 + (mi & 3) * 16 + g * 4;
#pragma unroll
      for (int ni = 0; ni < 4; ni++) {
        int col = n0l + (ni >> 1) * 128 + wc * 32 + (ni & 1) * 16 + ln;
        int h = col >> 7, hd = col & 127;
        bf16x4 o;
#pragma unroll
        for (int r2 = 0; r2 < 4; r2++) o[r2] = (bf16)acc[mi][ni][r2];
        *(bf16x4*)(vt + (((size_t)(bix * Hh + h) * HDd + hd) * Ss + sl)) = o;
      }
    }
  } else {
    bf16* dst = (z == 0) ? q : k;
    float* T = (float*)SLM;                 // stride 260 floats (1040 B, conflict-free pad)
    const float c1 = 0.14391156642398168f;  // ln(10000)/64
    int cg = (tid & 31) * 8;                // per-thread column base (8 consecutive cols)
    int hb = n0l + cg;
    int hh = hb >> 7, hd0 = hb & 127;       // constant per thread
    float fr[4];
#pragma unroll
    for (int pr = 0; pr < 4; pr++)
      fr[pr] = __expf(-(float)((hd0 >> 1) + pr) * c1);

#pragma unroll
    for (int pass = 0; pass < 2; pass++) {
      __syncthreads();
      // scatter this pass's 128 rows of acc into LDS (f32, exact)
#pragma unroll
      for (int mi2 = 0; mi2 < 4; mi2++) {
#pragma unroll
        for (int ni = 0; ni < 4; ni++) {
          int c = (ni >> 1) * 128 + wc * 32 + (ni & 1) * 16 + ln;
          int rb = wr * 64 + mi2 * 16 + g * 4;
#pragma unroll
          for (int r2 = 0; r2 < 4; r2++)
            T[(rb + r2) * 260 + c] = acc[pass * 4 + mi2][ni][r2];
        }
      }
      __syncthreads();
      // gather rows: 8 consecutive hd per thread, RoPE pairs in-register, 16 B stores
#pragma unroll
      for (int j = 0; j < 8; j++) {
        int r = j * 16 + (tid >> 5);
        int sg = m0 + pass * 128 + r;
        float p = (float)pos[sg];
        f32x4 v0 = *(const f32x4*)(T + r * 260 + cg);
        f32x4 v1 = *(const f32x4*)(T + r * 260 + cg + 4);
        float e0[4] = {v0[0], v0[2], v1[0], v1[2]};
        float e1[4] = {v0[1], v0[3], v1[1], v1[3]};
        int s = sg & 2047;
        bf16x8 o;
#pragma unroll
        for (int pr = 0; pr < 4; pr++) {
          float ang = p * fr[pr];
          float sn, cs;
          __sincosf(ang, &sn, &cs);
          o[2 * pr]     = (bf16)(e0[pr] * cs - e1[pr] * sn);
          o[2 * pr + 1] = (bf16)(e1[pr] * cs + e0[pr] * sn);
        }
        *(bf16x8*)(dst + (((size_t)(bix * Hh + hh) * Ss + s) * HDd + hd0)) = o;
      }
    }
  }
}

// ------------- final projection + bias (fp32 out), 128x256 tiles, 256 blocks = full GPU -------------
__global__ __launch_bounds__(512, 2) void k_out128(const bf16* __restrict__ ctx,
                                                   const bf16* __restrict__ wot,
                                                   const float* __restrict__ bo,
                                                   float* __restrict__ outp) {
  __shared__ char AL[32768];
  __shared__ char BL[65536];
  int bid = blockIdx.x;                    // 256 blocks
  int x = bid & 7, j = bid >> 3;           // XCD x gets an 8(mt) x 4(nt) chunk
  int mt = (x >> 1) * 8 + (j >> 2);
  int nt = (x & 1) * 4 + (j & 3);
  int m0 = mt * 128, n0 = nt * 256;

  f32x4 acc[4][4];
  gemm128_core(ctx, wot, m0, n0, AL, BL, acc);

  const int l = threadIdx.x & 63, w = threadIdx.x >> 6;
  const int wr = w >> 2, wc = w & 3, g = l >> 4, ln = l & 15;
  float bov[4];
#pragma unroll
  for (int ni = 0; ni < 4; ni++)
    bov[ni] = bo[n0 + (ni >> 1) * 128 + wc * 32 + (ni & 1) * 16 + ln];
#pragma unroll
  for (int mq = 0; mq < 4; mq++)
#pragma unroll
    for (int r2 = 0; r2 < 4; r2++) {
      int row = m0 + wr * 64 + mq * 16 + g * 4 + r2;
#pragma unroll
      for (int ni = 0; ni < 4; ni++) {
        int col = n0 + (ni >> 1) * 128 + wc * 32 + (ni & 1) * 16 + ln;
        outp[(size_t)row * Dd + col] = acc[mq][ni][r2] + bov[ni];
      }
    }
}

// ------------- flash attention with doc+causal mask -------------
__global__ __launch_bounds__(256) void k_attn(const bf16* __restrict__ q,
                                              const bf16* __restrict__ k,
                                              const bf16* __restrict__ vt,
                                              const int* __restrict__ pos,
                                              bf16* __restrict__ ctx) {
  __shared__ bf16 Ks[64 * 128];    // K tile  [kv][hd]
  __shared__ bf16 Vts[128 * 64];   // Vt tile [hd][kv]
  __shared__ bf16 Pw[4][16 * 64];  // per-wave P [qrow][kv]
  int bh = blockIdx.y;
  int b = bh >> 4, h = bh & 15;
  int qt = blockIdx.x, q0 = qt * 64;
  const int tid = threadIdx.x, l = tid & 63, w = tid >> 6, g = l >> 4, ln = l & 15;
  const bf16* qb = q + (size_t)bh * Ss * HDd;
  const bf16* kb = k + (size_t)bh * Ss * HDd;
  const bf16* vb = vt + (size_t)bh * Ss * HDd;

  bf16x8 qf[4];
  int qr = q0 + w * 16 + ln;
#pragma unroll
  for (int ks = 0; ks < 4; ks++)
    qf[ks] = *(const bf16x8*)(qb + (size_t)qr * HDd + ks * 32 + 8 * g);

  int rrow[4], dstart[4];
  float m[4], lsum[4];
#pragma unroll
  for (int r2 = 0; r2 < 4; r2++) {
    rrow[r2] = q0 + w * 16 + 4 * g + r2;
    dstart[r2] = rrow[r2] - pos[(size_t)b * Ss + rrow[r2]];
    m[r2] = -1e30f;
    lsum[r2] = 0.f;
  }
  f32x4 oacc[8];
  f32x4 z = {0.f, 0.f, 0.f, 0.f};
#pragma unroll
  for (int n = 0; n < 8; n++) oacc[n] = z;

  int kt_start = (q0 - pos[(size_t)b * Ss + q0]) >> 6;
  const float iscale = 0.08838834764831845f;  // 1/sqrt(128)

  for (int kt = kt_start; kt <= qt; kt++) {
    int kv0 = kt * 64;
#pragma unroll
    for (int i2 = 0; i2 < 4; i2++) {
      int o = i2 * 4096 + w * 1024 + l * 16;
      int rk = o >> 8, cbk = o & 255;
      gload_lds16((const char*)kb + (size_t)(kv0 + rk) * 256 + cbk,
                  (char*)Ks + i2 * 4096 + w * 1024);
      int rv = o >> 7, cbv = o & 127;
      gload_lds16((const char*)vb + (size_t)rv * (Ss * 2) + (size_t)kv0 * 2 + cbv,
                  (char*)Vts + i2 * 4096 + w * 1024);
    }
    __syncthreads();

    f32x4 sc[4];
#pragma unroll
    for (int n = 0; n < 4; n++) {
      f32x4 a = z;
#pragma unroll
      for (int ks = 0; ks < 4; ks++) {
        bf16x8 bfrag = *(const bf16x8*)(Ks + (n * 16 + ln) * 128 + ks * 32 + 8 * g);
        a = __builtin_amdgcn_mfma_f32_16x16x32_bf16(qf[ks], bfrag, a, 0, 0, 0);
      }
      sc[n] = a;
    }

    float pmax[4] = {-1e30f, -1e30f, -1e30f, -1e30f};
    float pv[4][4];
#pragma unroll
    for (int n = 0; n < 4; n++) {
      int kvc = kv0 + n * 16 + ln;
#pragma unroll
      for (int r2 = 0; r2 < 4; r2++) {
        bool ok = (kvc <= rrow[r2]) && (kvc >= dstart[r2]);
        float sv = ok ? sc[n][r2] * iscale : -1e30f;
        pv[n][r2] = sv;
        pmax[r2] = fmaxf(pmax[r2], sv);
      }
    }
#pragma unroll
    for (int off = 1; off < 16; off <<= 1)
#pragma unroll
      for (int r2 = 0; r2 < 4; r2++)
        pmax[r2] = fmaxf(pmax[r2], __shfl_xor(pmax[r2], off, 64));

    float alpha[4];
#pragma unroll
    for (int r2 = 0; r2 < 4; r2++) {
      float mn = fmaxf(m[r2], pmax[r2]);
      alpha[r2] = __expf(m[r2] - mn);
      m[r2] = mn;
    }

    float rs[4] = {0.f, 0.f, 0.f, 0.f};
#pragma unroll
    for (int n = 0; n < 4; n++) {
      int kvc = kv0 + n * 16 + ln;
#pragma unroll
      for (int r2 = 0; r2 < 4; r2++) {
        bool ok = (kvc <= rrow[r2]) && (kvc >= dstart[r2]);
        float p = ok ? __expf(pv[n][r2] - m[r2]) : 0.f;
        rs[r2] += p;
        Pw[w][(4 * g + r2) * 64 + n * 16 + ln] = (bf16)p;
      }
    }
#pragma unroll
    for (int off = 1; off < 16; off <<= 1)
#pragma unroll
      for (int r2 = 0; r2 < 4; r2++) rs[r2] += __shfl_xor(rs[r2], off, 64);
#pragma unroll
    for (int r2 = 0; r2 < 4; r2++) lsum[r2] = lsum[r2] * alpha[r2] + rs[r2];
#pragma unroll
    for (int n = 0; n < 8; n++)
#pragma unroll
      for (int r2 = 0; r2 < 4; r2++) oacc[n][r2] *= alpha[r2];
    __syncthreads();

#pragma unroll
    for (int n = 0; n < 8; n++) {
#pragma unroll
      for (int ks = 0; ks < 2; ks++) {
        bf16x8 pa = *(const bf16x8*)(&Pw[w][ln * 64 + ks * 32 + 8 * g]);
        bf16x8 vfr = *(const bf16x8*)(Vts + (n * 16 + ln) * 64 + ks * 32 + 8 * g);
        oacc[n] = __builtin_amdgcn_mfma_f32_16x16x32_bf16(pa, vfr, oacc[n], 0, 0, 0);
      }
    }
    __syncthreads();
  }

#pragma unroll
  for (int n = 0; n < 8; n++)
#pragma unroll
    for (int r2 = 0; r2 < 4; r2++) {
      float val = oacc[n][r2] / lsum[r2];
      ctx[((size_t)(b * Ss + rrow[r2])) * Dd + h * HDd + n * 16 + ln] = (bf16)val;
    }
}

extern "C" void kernel_launch(void* const* d_in, const int* in_sizes, int n_in,
                              void* d_out, int out_size, void* d_ws, size_t ws_size,
                              hipStream_t stream) {
  const float* x = (const float*)d_in[0];
  const int* doc = (const int*)d_in[1];
  const float* Wq = (const float*)d_in[2];
  const float* Wk = (const float*)d_in[3];
  const float* Wv = (const float*)d_in[4];
  const float* Wo = (const float*)d_in[5];
  const float* bo = (const float*)d_in[6];
  float* outp = (float*)d_out;

  char* ws = (char*)d_ws;
  size_t off = 0;
  auto alloc = [&](size_t bytes) {
    char* p = ws + off;
    off += (bytes + 255) & ~(size_t)255;
    return p;
  };
  bf16* xb = (bf16*)alloc((size_t)BSs * Dd * 2);
  bf16* wqkvt = (bf16*)alloc((size_t)3 * Dd * Dd * 2);  // [6144][2048]
  bf16* wot = (bf16*)alloc((size_t)Dd * Dd * 2);
  bf16* qd = (bf16*)alloc((size_t)BSs * Dd * 2);
  bf16* kd = (bf16*)alloc((size_t)BSs * Dd * 2);
  bf16* vtd = (bf16*)alloc((size_t)BSs * Dd * 2);  // V stored transposed directly
  bf16* ctxd = (bf16*)alloc((size_t)BSs * Dd * 2);
  int* pos = (int*)alloc((size_t)BSs * 4);

  k_cvtx<<<(BSs * Dd) / 1024, 256, 0, stream>>>(x, xb);
  k_tw<<<dim3(Dd / 64, Dd / 64, 4), 256, 0, stream>>>(
      Wq, Wk, Wv, Wo, wqkvt, wqkvt + (size_t)Dd * Dd, wqkvt + (size_t)2 * Dd * Dd, wot);
  k_pos<<<Bb, 1024, 0, stream>>>(doc, pos);
  k_qkv256<<<dim3(384), 512, 0, stream>>>(xb, wqkvt, pos, qd, kd, vtd);
  k_attn<<<dim3(Ss / 64, Bb * Hh), 256, 0, stream>>>(qd, kd, vtd, pos, ctxd);
  k_out128<<<dim3(256), 512, 0, stream>>>(ctxd, wot, bo, outp);
}

// Round 2
// 242.210 us; speedup vs baseline: 1.1535x; 1.0040x over previous
//
#include <hip/hip_runtime.h>
#include <hip/hip_bf16.h>

#define Dd 2048
#define Ss 2048
#define Bb 2
#define Hh 16
#define HDd 128
#define BSs (Bb*Ss)
#define NTILES 32  // 2048 / 64

typedef __bf16 bf16;
typedef __bf16 bf16x8 __attribute__((ext_vector_type(8)));
typedef __bf16 bf16x4 __attribute__((ext_vector_type(4)));
typedef float f32x4 __attribute__((ext_vector_type(4)));

__device__ __forceinline__ void gload_lds16(const void* g, void* l) {
  __builtin_amdgcn_global_load_lds((__attribute__((address_space(1))) void*)(g),
                                   (__attribute__((address_space(3))) void*)(l), 16, 0, 0);
}

template <int N>
__device__ __forceinline__ void waitv() {
  if constexpr (N == 0) asm volatile("s_waitcnt vmcnt(0)" ::: "memory");
  else if constexpr (N == 2) asm volatile("s_waitcnt vmcnt(2)" ::: "memory");
  else if constexpr (N == 4) asm volatile("s_waitcnt vmcnt(4)" ::: "memory");
  else if constexpr (N == 6) asm volatile("s_waitcnt vmcnt(6)" ::: "memory");
  else if constexpr (N == 8) asm volatile("s_waitcnt vmcnt(8)" ::: "memory");
  else if constexpr (N == 10) asm volatile("s_waitcnt vmcnt(10)" ::: "memory");
  // N < 0: no wait
}

// ---------------- x -> bf16 ----------------
__global__ void k_cvtx(const float* __restrict__ x, bf16* __restrict__ xb) {
  int i = (blockIdx.x * 256 + threadIdx.x) * 4;
  f32x4 v = *(const f32x4*)(x + i);
  bf16x4 o;
  o[0] = (bf16)v[0]; o[1] = (bf16)v[1]; o[2] = (bf16)v[2]; o[3] = (bf16)v[3];
  *(bf16x4*)(xb + i) = o;
}

// ------------- W [K][N] fp32 -> Wt [N][K] bf16 (x4 weights), 64x64 tiles, vectorized -------------
__global__ void k_tw(const float* __restrict__ W0, const float* __restrict__ W1,
                     const float* __restrict__ W2, const float* __restrict__ W3,
                     bf16* __restrict__ T0, bf16* __restrict__ T1,
                     bf16* __restrict__ T2, bf16* __restrict__ T3) {
  const float* W; bf16* T;
  switch (blockIdx.z) {
    case 0: W = W0; T = T0; break;
    case 1: W = W1; T = T1; break;
    case 2: W = W2; T = T2; break;
    default: W = W3; T = T3; break;
  }
  __shared__ float t[64][65];
  int n0 = blockIdx.x * 64, k0 = blockIdx.y * 64;
  int tid = threadIdx.x;  // 256
#pragma unroll
  for (int rr = 0; rr < 4; rr++) {
    int r = (tid >> 4) + rr * 16;
    f32x4 vv = *(const f32x4*)(W + (size_t)(k0 + r) * Dd + n0 + (tid & 15) * 4);
#pragma unroll
    for (int j = 0; j < 4; j++) t[r][(tid & 15) * 4 + j] = vv[j];
  }
  __syncthreads();
#pragma unroll
  for (int rr = 0; rr < 4; rr++) {
    int n = rr * 16 + (tid >> 4);
    int kb = (tid & 15) * 4;
    bf16x4 o;
#pragma unroll
    for (int j = 0; j < 4; j++) o[j] = (bf16)t[kb + j][n];
    *(bf16x4*)(T + (size_t)(n0 + n) * Dd + k0 + kb) = o;
  }
}

// ------------- doc position ids (prefix-max scan per batch) -------------
__global__ void k_pos(const int* __restrict__ doc, int* __restrict__ pos) {
  int b = blockIdx.x;
  __shared__ int bp[2][Ss];
  const int* db = doc + (size_t)b * Ss;
  for (int i = threadIdx.x; i < Ss; i += 1024) {
    int bd = (i == 0) || (db[i] != db[i - 1]);
    bp[0][i] = bd ? i : 0;
  }
  __syncthreads();
  int src = 0;
  for (int off = 1; off < Ss; off <<= 1) {
    for (int i = threadIdx.x; i < Ss; i += 1024) {
      int v = bp[src][i];
      if (i >= off) v = max(v, bp[src][i - off]);
      bp[1 - src][i] = v;
    }
    __syncthreads();
    src = 1 - src;
  }
  for (int i = threadIdx.x; i < Ss; i += 1024)
    pos[(size_t)b * Ss + i] = i - bp[src][i];
}

__device__ __forceinline__ bf16x8 lds_frag(const char* buf, int row, int cb) {
  return *(const bf16x8*)(buf + row * 128 + (cb ^ ((row & 7) << 4)));
}

// ================= 128x256 2-phase GEMM core (deep prefetch) =================
// A [M][2048], B [N][2048]. Tile 128x256. 8 waves as 2(M) x 4(N), wave tile 64x64.
// LDS: 2 dbuf x (A [128][64]=16K + B [256][64]=32K) = 96 KiB.
// Slots: s0=A (2 loads), s1=B-up (2), s2=B-lo (2). Burst all 3 slots of t+1 at ph0 of t.
// Ledger: entry outstanding = s2(t) (2); ph0 issues 6 -> 8, vmcnt(6) retires s2(t);
//         ph1 vmcnt(2) retires s0,s1(t+1). Last tile: vmcnt(0) / no wait.
__device__ __forceinline__ void stage_slot128(const bf16* gA, const bf16* gB,
                                              int m0, int n0, int t, int slot,
                                              char* AL, char* BL, int tid) {
  const char* gp; char* l; int rbase;
  char* bufA = AL + (size_t)((t & 1) * 16384);
  char* bufB = BL + (size_t)((t & 1) * 32768);
  if (slot == 0)      { gp = (const char*)gA; l = bufA;         rbase = m0; }
  else if (slot == 1) { gp = (const char*)gB; l = bufB;         rbase = n0; }
  else                { gp = (const char*)gB; l = bufB + 16384; rbase = n0 + 128; }
  int ktb = t * 128;
#pragma unroll
  for (int p = 0; p < 2; p++) {
    int o = p * 8192 + tid * 16;
    int r = o >> 7, cb = o & 127;
    gload_lds16(gp + (size_t)(rbase + r) * 4096 + ktb + (cb ^ ((r & 7) << 4)), l + o);
  }
}

template <bool STAGE, int WV0, int WV1>
__device__ __forceinline__ void do_tile128(const bf16* gA, const bf16* gB, int m0, int n0,
                                           int t, char* AL, char* BL, int tid,
                                           int wr, int wc, int ln, int g,
                                           f32x4 acc[4][4]) {
  const char* tileA = AL + (size_t)((t & 1) * 16384);
  const char* tileB = BL + (size_t)((t & 1) * 32768);
  bf16x8 af[4][2], bf_[2][2];

  // ---- phase 0: read A + B-up of t; burst stage t+1; retire s2(t) ----
#pragma unroll
  for (int mq = 0; mq < 4; mq++)
#pragma unroll
    for (int kk = 0; kk < 2; kk++)
      af[mq][kk] = lds_frag(tileA, wr * 64 + mq * 16 + ln, kk * 64 + g * 16);
#pragma unroll
  for (int nq = 0; nq < 2; nq++)
#pragma unroll
    for (int kk = 0; kk < 2; kk++)
      bf_[nq][kk] = lds_frag(tileB, wc * 32 + nq * 16 + ln, kk * 64 + g * 16);
  if (STAGE) {
    stage_slot128(gA, gB, m0, n0, t + 1, 0, AL, BL, tid);
    stage_slot128(gA, gB, m0, n0, t + 1, 1, AL, BL, tid);
    stage_slot128(gA, gB, m0, n0, t + 1, 2, AL, BL, tid);
  }
  waitv<WV0>();
  __builtin_amdgcn_s_barrier();
  __builtin_amdgcn_s_setprio(1);
#pragma unroll
  for (int mq = 0; mq < 4; mq++)
#pragma unroll
    for (int nq = 0; nq < 2; nq++)
#pragma unroll
      for (int kk = 0; kk < 2; kk++)
        acc[mq][nq] = __builtin_amdgcn_mfma_f32_16x16x32_bf16(af[mq][kk], bf_[nq][kk], acc[mq][nq], 0, 0, 0);
  __builtin_amdgcn_s_setprio(0);
  __builtin_amdgcn_s_barrier();

  // ---- phase 1: read B-lo of t; retire s0,s1(t+1) ----
#pragma unroll
  for (int nq = 0; nq < 2; nq++)
#pragma unroll
    for (int kk = 0; kk < 2; kk++)
      bf_[nq][kk] = lds_frag(tileB, 128 + wc * 32 + nq * 16 + ln, kk * 64 + g * 16);
  waitv<WV1>();
  __builtin_amdgcn_s_barrier();
  __builtin_amdgcn_s_setprio(1);
#pragma unroll
  for (int mq = 0; mq < 4; mq++)
#pragma unroll
    for (int nq = 0; nq < 2; nq++)
#pragma unroll
      for (int kk = 0; kk < 2; kk++)
        acc[mq][2 + nq] = __builtin_amdgcn_mfma_f32_16x16x32_bf16(af[mq][kk], bf_[nq][kk], acc[mq][2 + nq], 0, 0, 0);
  __builtin_amdgcn_s_setprio(0);
  __builtin_amdgcn_s_barrier();
}

__device__ __forceinline__ void gemm128_core(const bf16* gA, const bf16* gB,
                                             int m0, int n0, char* AL, char* BL,
                                             f32x4 acc[4][4]) {
  const int tid = threadIdx.x;
  const int l = tid & 63, w = tid >> 6;
  const int wr = w >> 2, wc = w & 3;
  const int g = l >> 4, ln = l & 15;
  f32x4 z = {0.f, 0.f, 0.f, 0.f};
#pragma unroll
  for (int i = 0; i < 4; i++)
#pragma unroll
    for (int n = 0; n < 4; n++) acc[i][n] = z;

  // prologue: stage all 3 slots of tile 0; retire s0,s1 (leave s2 = 2)
  stage_slot128(gA, gB, m0, n0, 0, 0, AL, BL, tid);
  stage_slot128(gA, gB, m0, n0, 0, 1, AL, BL, tid);
  stage_slot128(gA, gB, m0, n0, 0, 2, AL, BL, tid);
  waitv<2>();
  __builtin_amdgcn_s_barrier();

  for (int t = 0; t < NTILES - 1; t++)
    do_tile128<true, 6, 2>(gA, gB, m0, n0, t, AL, BL, tid, wr, wc, ln, g, acc);
  do_tile128<false, 0, -1>(gA, gB, m0, n0, NTILES - 1, AL, BL, tid, wr, wc, ln, g, acc);
}

// ------------- fused QKV projection + RoPE epilogue (128x256 tiles, 768 blocks = 3 exact rounds) -------------
// gB = wqkvt [6144][2048]; cols 0-2047 -> Q, 2048-4095 -> K, 4096-6143 -> V.
// Q,K out: [B][H][S][HD] (LDS-transpose epilogue in 2 passes of 64 rows, in-register RoPE pairs).
// V out: DIRECT transposed [B][H][HD][S] bf16x4 stores (r2-quad = 4 consecutive s).
__global__ __launch_bounds__(512, 2) void k_qkv128(const bf16* __restrict__ xb,
                                                   const bf16* __restrict__ wqkvt,
                                                   const int* __restrict__ pos,
                                                   bf16* __restrict__ q,
                                                   bf16* __restrict__ k,
                                                   bf16* __restrict__ vt) {
  __shared__ char SLM[98304];  // GEMM: A dbuf 32K + B dbuf 64K; epilogue: 64x260 f32 view (65 KB)
  char* AL = SLM;
  char* BL = SLM + 32768;
  int bid = blockIdx.x;                    // 768 blocks
  int idx = (bid & 7) * 96 + (bid >> 3);   // XCD swizzle (768 % 8 == 0)
  int mt = idx / 24, nt = idx % 24;        // same-XCD neighbors share mt -> A-panel L2 reuse
  int m0 = mt * 128, n0 = nt * 256;

  f32x4 acc[4][4];
  gemm128_core(xb, wqkvt, m0, n0, AL, BL, acc);

  const int tid = threadIdx.x;
  const int l = tid & 63, w = tid >> 6;
  const int wr = w >> 2, wc = w & 3, g = l >> 4, ln = l & 15;
  int z = n0 >> 11;                         // 0=Q 1=K 2=V (block-uniform)
  int n0l = n0 & 2047;
  int bix = m0 >> 11;
  int sl0 = m0 & 2047;                      // 128-row tile never crosses batch boundary

  if (z == 2) {
    // V: straight from acc, transposed layout [B][H][HD][S], 8 B stores
#pragma unroll
    for (int mq = 0; mq < 4; mq++) {
      int sl = sl0 + wr * 64 + mq * 16 + g * 4;
#pragma unroll
      for (int ni = 0; ni < 4; ni++) {
        int col = n0l + (ni >> 1) * 128 + wc * 32 + (ni & 1) * 16 + ln;
        int h = col >> 7, hd = col & 127;
        bf16x4 o;
#pragma unroll
        for (int r2 = 0; r2 < 4; r2++) o[r2] = (bf16)acc[mq][ni][r2];
        *(bf16x4*)(vt + (((size_t)(bix * Hh + h) * HDd + hd) * Ss + sl)) = o;
      }
    }
  } else {
    bf16* dst = (z == 0) ? q : k;
    float* T = (float*)SLM;                 // stride 260 floats, 64 rows per pass (65 KB < 96 KiB)
    const float c1 = 0.14391156642398168f;  // ln(10000)/64
    int cg = (tid & 31) * 8;                // per-thread column base (8 consecutive cols)
    int hb = n0l + cg;
    int hh = hb >> 7, hd0 = hb & 127;       // constant per thread
    float fr[4];
#pragma unroll
    for (int pr = 0; pr < 4; pr++)
      fr[pr] = __expf(-(float)((hd0 >> 1) + pr) * c1);

#pragma unroll
    for (int pass = 0; pass < 2; pass++) {
      __syncthreads();
      // scatter 64 rows of acc into LDS (waves with wr==pass own these rows)
      if (wr == pass) {
#pragma unroll
        for (int mq = 0; mq < 4; mq++) {
#pragma unroll
          for (int ni = 0; ni < 4; ni++) {
            int c = (ni >> 1) * 128 + wc * 32 + (ni & 1) * 16 + ln;
            int rb = mq * 16 + g * 4;
#pragma unroll
            for (int r2 = 0; r2 < 4; r2++)
              T[(rb + r2) * 260 + c] = acc[mq][ni][r2];
          }
        }
      }
      __syncthreads();
      // gather rows: 8 consecutive hd per thread, RoPE pairs in-register, 16 B stores
#pragma unroll
      for (int j = 0; j < 4; j++) {
        int r = j * 16 + (tid >> 5);
        int sg = m0 + pass * 64 + r;
        float p = (float)pos[sg];
        f32x4 v0 = *(const f32x4*)(T + r * 260 + cg);
        f32x4 v1 = *(const f32x4*)(T + r * 260 + cg + 4);
        float e0[4] = {v0[0], v0[2], v1[0], v1[2]};
        float e1[4] = {v0[1], v0[3], v1[1], v1[3]};
        int s = sg & 2047;
        bf16x8 o;
#pragma unroll
        for (int pr = 0; pr < 4; pr++) {
          float ang = p * fr[pr];
          float sn, cs;
          __sincosf(ang, &sn, &cs);
          o[2 * pr]     = (bf16)(e0[pr] * cs - e1[pr] * sn);
          o[2 * pr + 1] = (bf16)(e1[pr] * cs + e0[pr] * sn);
        }
        *(bf16x8*)(dst + (((size_t)(bix * Hh + hh) * Ss + s) * HDd + hd0)) = o;
      }
    }
  }
}

// ------------- final projection + bias (fp32 out), 128x256 tiles, 256 blocks = full GPU -------------
__global__ __launch_bounds__(512, 2) void k_out128(const bf16* __restrict__ ctx,
                                                   const bf16* __restrict__ wot,
                                                   const float* __restrict__ bo,
                                                   float* __restrict__ outp) {
  __shared__ char AL[32768];
  __shared__ char BL[65536];
  int bid = blockIdx.x;                    // 256 blocks
  int x = bid & 7, j = bid >> 3;           // XCD x gets an 8(mt) x 4(nt) chunk
  int mt = (x >> 1) * 8 + (j >> 2);
  int nt = (x & 1) * 4 + (j & 3);
  int m0 = mt * 128, n0 = nt * 256;

  f32x4 acc[4][4];
  gemm128_core(ctx, wot, m0, n0, AL, BL, acc);

  const int l = threadIdx.x & 63, w = threadIdx.x >> 6;
  const int wr = w >> 2, wc = w & 3, g = l >> 4, ln = l & 15;
  float bov[4];
#pragma unroll
  for (int ni = 0; ni < 4; ni++)
    bov[ni] = bo[n0 + (ni >> 1) * 128 + wc * 32 + (ni & 1) * 16 + ln];
#pragma unroll
  for (int mq = 0; mq < 4; mq++)
#pragma unroll
    for (int r2 = 0; r2 < 4; r2++) {
      int row = m0 + wr * 64 + mq * 16 + g * 4 + r2;
#pragma unroll
      for (int ni = 0; ni < 4; ni++) {
        int col = n0 + (ni >> 1) * 128 + wc * 32 + (ni & 1) * 16 + ln;
        outp[(size_t)row * Dd + col] = acc[mq][ni][r2] + bov[ni];
      }
    }
}

// ------------- flash attention with doc+causal mask -------------
__global__ __launch_bounds__(256) void k_attn(const bf16* __restrict__ q,
                                              const bf16* __restrict__ k,
                                              const bf16* __restrict__ vt,
                                              const int* __restrict__ pos,
                                              bf16* __restrict__ ctx) {
  __shared__ bf16 Ks[64 * 128];    // K tile  [kv][hd]
  __shared__ bf16 Vts[128 * 64];   // Vt tile [hd][kv]
  __shared__ bf16 Pw[4][16 * 64];  // per-wave P [qrow][kv]
  int bh = blockIdx.y;
  int b = bh >> 4, h = bh & 15;
  int qt = blockIdx.x, q0 = qt * 64;
  const int tid = threadIdx.x, l = tid & 63, w = tid >> 6, g = l >> 4, ln = l & 15;
  const bf16* qb = q + (size_t)bh * Ss * HDd;
  const bf16* kb = k + (size_t)bh * Ss * HDd;
  const bf16* vb = vt + (size_t)bh * Ss * HDd;

  bf16x8 qf[4];
  int qr = q0 + w * 16 + ln;
#pragma unroll
  for (int ks = 0; ks < 4; ks++)
    qf[ks] = *(const bf16x8*)(qb + (size_t)qr * HDd + ks * 32 + 8 * g);

  int rrow[4], dstart[4];
  float m[4], lsum[4];
#pragma unroll
  for (int r2 = 0; r2 < 4; r2++) {
    rrow[r2] = q0 + w * 16 + 4 * g + r2;
    dstart[r2] = rrow[r2] - pos[(size_t)b * Ss + rrow[r2]];
    m[r2] = -1e30f;
    lsum[r2] = 0.f;
  }
  f32x4 oacc[8];
  f32x4 z = {0.f, 0.f, 0.f, 0.f};
#pragma unroll
  for (int n = 0; n < 8; n++) oacc[n] = z;

  int kt_start = (q0 - pos[(size_t)b * Ss + q0]) >> 6;
  const float iscale = 0.08838834764831845f;  // 1/sqrt(128)

  for (int kt = kt_start; kt <= qt; kt++) {
    int kv0 = kt * 64;
#pragma unroll
    for (int i2 = 0; i2 < 4; i2++) {
      int o = i2 * 4096 + w * 1024 + l * 16;
      int rk = o >> 8, cbk = o & 255;
      gload_lds16((const char*)kb + (size_t)(kv0 + rk) * 256 + cbk,
                  (char*)Ks + i2 * 4096 + w * 1024);
      int rv = o >> 7, cbv = o & 127;
      gload_lds16((const char*)vb + (size_t)rv * (Ss * 2) + (size_t)kv0 * 2 + cbv,
                  (char*)Vts + i2 * 4096 + w * 1024);
    }
    __syncthreads();

    f32x4 sc[4];
#pragma unroll
    for (int n = 0; n < 4; n++) {
      f32x4 a = z;
#pragma unroll
      for (int ks = 0; ks < 4; ks++) {
        bf16x8 bfrag = *(const bf16x8*)(Ks + (n * 16 + ln) * 128 + ks * 32 + 8 * g);
        a = __builtin_amdgcn_mfma_f32_16x16x32_bf16(qf[ks], bfrag, a, 0, 0, 0);
      }
      sc[n] = a;
    }

    float pmax[4] = {-1e30f, -1e30f, -1e30f, -1e30f};
    float pv[4][4];
#pragma unroll
    for (int n = 0; n < 4; n++) {
      int kvc = kv0 + n * 16 + ln;
#pragma unroll
      for (int r2 = 0; r2 < 4; r2++) {
        bool ok = (kvc <= rrow[r2]) && (kvc >= dstart[r2]);
        float sv = ok ? sc[n][r2] * iscale : -1e30f;
        pv[n][r2] = sv;
        pmax[r2] = fmaxf(pmax[r2], sv);
      }
    }
#pragma unroll
    for (int off = 1; off < 16; off <<= 1)
#pragma unroll
      for (int r2 = 0; r2 < 4; r2++)
        pmax[r2] = fmaxf(pmax[r2], __shfl_xor(pmax[r2], off, 64));

    float alpha[4];
#pragma unroll
    for (int r2 = 0; r2 < 4; r2++) {
      float mn = fmaxf(m[r2], pmax[r2]);
      alpha[r2] = __expf(m[r2] - mn);
      m[r2] = mn;
    }

    float rs[4] = {0.f, 0.f, 0.f, 0.f};
#pragma unroll
    for (int n = 0; n < 4; n++) {
      int kvc = kv0 + n * 16 + ln;
#pragma unroll
      for (int r2 = 0; r2 < 4; r2++) {
        bool ok = (kvc <= rrow[r2]) && (kvc >= dstart[r2]);
        float p = ok ? __expf(pv[n][r2] - m[r2]) : 0.f;
        rs[r2] += p;
        Pw[w][(4 * g + r2) * 64 + n * 16 + ln] = (bf16)p;
      }
    }
#pragma unroll
    for (int off = 1; off < 16; off <<= 1)
#pragma unroll
      for (int r2 = 0; r2 < 4; r2++) rs[r2] += __shfl_xor(rs[r2], off, 64);
#pragma unroll
    for (int r2 = 0; r2 < 4; r2++) lsum[r2] = lsum[r2] * alpha[r2] + rs[r2];
#pragma unroll
    for (int n = 0; n < 8; n++)
#pragma unroll
      for (int r2 = 0; r2 < 4; r2++) oacc[n][r2] *= alpha[r2];
    __syncthreads();

#pragma unroll
    for (int n = 0; n < 8; n++) {
#pragma unroll
      for (int ks = 0; ks < 2; ks++) {
        bf16x8 pa = *(const bf16x8*)(&Pw[w][ln * 64 + ks * 32 + 8 * g]);
        bf16x8 vfr = *(const bf16x8*)(Vts + (n * 16 + ln) * 64 + ks * 32 + 8 * g);
        oacc[n] = __builtin_amdgcn_mfma_f32_16x16x32_bf16(pa, vfr, oacc[n], 0, 0, 0);
      }
    }
    __syncthreads();
  }

#pragma unroll
  for (int n = 0; n < 8; n++)
#pragma unroll
    for (int r2 = 0; r2 < 4; r2++) {
      float val = oacc[n][r2] / lsum[r2];
      ctx[((size_t)(b * Ss + rrow[r2])) * Dd + h * HDd + n * 16 + ln] = (bf16)val;
    }
}

extern "C" void kernel_launch(void* const* d_in, const int* in_sizes, int n_in,
                              void* d_out, int out_size, void* d_ws, size_t ws_size,
                              hipStream_t stream) {
  const float* x = (const float*)d_in[0];
  const int* doc = (const int*)d_in[1];
  const float* Wq = (const float*)d_in[2];
  const float* Wk = (const float*)d_in[3];
  const float* Wv = (const float*)d_in[4];
  const float* Wo = (const float*)d_in[5];
  const float* bo = (const float*)d_in[6];
  float* outp = (float*)d_out;

  char* ws = (char*)d_ws;
  size_t off = 0;
  auto alloc = [&](size_t bytes) {
    char* p = ws + off;
    off += (bytes + 255) & ~(size_t)255;
    return p;
  };
  bf16* xb = (bf16*)alloc((size_t)BSs * Dd * 2);
  bf16* wqkvt = (bf16*)alloc((size_t)3 * Dd * Dd * 2);  // [6144][2048]
  bf16* wot = (bf16*)alloc((size_t)Dd * Dd * 2);
  bf16* qd = (bf16*)alloc((size_t)BSs * Dd * 2);
  bf16* kd = (bf16*)alloc((size_t)BSs * Dd * 2);
  bf16* vtd = (bf16*)alloc((size_t)BSs * Dd * 2);  // V stored transposed directly
  bf16* ctxd = (bf16*)alloc((size_t)BSs * Dd * 2);
  int* pos = (int*)alloc((size_t)BSs * 4);

  k_cvtx<<<(BSs * Dd) / 1024, 256, 0, stream>>>(x, xb);
  k_tw<<<dim3(Dd / 64, Dd / 64, 4), 256, 0, stream>>>(
      Wq, Wk, Wv, Wo, wqkvt, wqkvt + (size_t)Dd * Dd, wqkvt + (size_t)2 * Dd * Dd, wot);
  k_pos<<<Bb, 1024, 0, stream>>>(doc, pos);
  k_qkv128<<<dim3(768), 512, 0, stream>>>(xb, wqkvt, pos, qd, kd, vtd);
  k_attn<<<dim3(Ss / 64, Bb * Hh), 256, 0, stream>>>(qd, kd, vtd, pos, ctxd);
  k_out128<<<dim3(256), 512, 0, stream>>>(ctxd, wot, bo, outp);
}

// Round 3
// 227.029 us; speedup vs baseline: 1.2306x; 1.0669x over previous
//
#include <hip/hip_runtime.h>
#include <hip/hip_bf16.h>

#define Dd 2048
#define Ss 2048
#define Bb 2
#define Hh 16
#define HDd 128
#define BSs (Bb*Ss)
#define NTILES 32  // 2048 / 64

typedef __bf16 bf16;
typedef __bf16 bf16x8 __attribute__((ext_vector_type(8)));
typedef __bf16 bf16x4 __attribute__((ext_vector_type(4)));
typedef float f32x4 __attribute__((ext_vector_type(4)));

__device__ __forceinline__ void gload_lds16(const void* g, void* l) {
  __builtin_amdgcn_global_load_lds((__attribute__((address_space(1))) void*)(g),
                                   (__attribute__((address_space(3))) void*)(l), 16, 0, 0);
}

template <int N>
__device__ __forceinline__ void waitv() {
  if constexpr (N == 0) asm volatile("s_waitcnt vmcnt(0)" ::: "memory");
  else if constexpr (N == 2) asm volatile("s_waitcnt vmcnt(2)" ::: "memory");
  else if constexpr (N == 4) asm volatile("s_waitcnt vmcnt(4)" ::: "memory");
  else if constexpr (N == 6) asm volatile("s_waitcnt vmcnt(6)" ::: "memory");
  else if constexpr (N == 8) asm volatile("s_waitcnt vmcnt(8)" ::: "memory");
  else if constexpr (N == 10) asm volatile("s_waitcnt vmcnt(10)" ::: "memory");
  // N < 0: no wait
}

// ---------------- x -> bf16 ----------------
__global__ void k_cvtx(const float* __restrict__ x, bf16* __restrict__ xb) {
  int i = (blockIdx.x * 256 + threadIdx.x) * 4;
  f32x4 v = *(const f32x4*)(x + i);
  bf16x4 o;
  o[0] = (bf16)v[0]; o[1] = (bf16)v[1]; o[2] = (bf16)v[2]; o[3] = (bf16)v[3];
  *(bf16x4*)(xb + i) = o;
}

// ------------- W [K][N] fp32 -> Wt [N][K] bf16 (x4 weights), 64x64 tiles, vectorized -------------
__global__ void k_tw(const float* __restrict__ W0, const float* __restrict__ W1,
                     const float* __restrict__ W2, const float* __restrict__ W3,
                     bf16* __restrict__ T0, bf16* __restrict__ T1,
                     bf16* __restrict__ T2, bf16* __restrict__ T3) {
  const float* W; bf16* T;
  switch (blockIdx.z) {
    case 0: W = W0; T = T0; break;
    case 1: W = W1; T = T1; break;
    case 2: W = W2; T = T2; break;
    default: W = W3; T = T3; break;
  }
  __shared__ float t[64][65];
  int n0 = blockIdx.x * 64, k0 = blockIdx.y * 64;
  int tid = threadIdx.x;  // 256
#pragma unroll
  for (int rr = 0; rr < 4; rr++) {
    int r = (tid >> 4) + rr * 16;
    f32x4 vv = *(const f32x4*)(W + (size_t)(k0 + r) * Dd + n0 + (tid & 15) * 4);
#pragma unroll
    for (int j = 0; j < 4; j++) t[r][(tid & 15) * 4 + j] = vv[j];
  }
  __syncthreads();
#pragma unroll
  for (int rr = 0; rr < 4; rr++) {
    int n = rr * 16 + (tid >> 4);
    int kb = (tid & 15) * 4;
    bf16x4 o;
#pragma unroll
    for (int j = 0; j < 4; j++) o[j] = (bf16)t[kb + j][n];
    *(bf16x4*)(T + (size_t)(n0 + n) * Dd + k0 + kb) = o;
  }
}

// ------------- doc position ids (prefix-max scan per batch) -------------
__global__ void k_pos(const int* __restrict__ doc, int* __restrict__ pos) {
  int b = blockIdx.x;
  __shared__ int bp[2][Ss];
  const int* db = doc + (size_t)b * Ss;
  for (int i = threadIdx.x; i < Ss; i += 1024) {
    int bd = (i == 0) || (db[i] != db[i - 1]);
    bp[0][i] = bd ? i : 0;
  }
  __syncthreads();
  int src = 0;
  for (int off = 1; off < Ss; off <<= 1) {
    for (int i = threadIdx.x; i < Ss; i += 1024) {
      int v = bp[src][i];
      if (i >= off) v = max(v, bp[src][i - off]);
      bp[1 - src][i] = v;
    }
    __syncthreads();
    src = 1 - src;
  }
  for (int i = threadIdx.x; i < Ss; i += 1024)
    pos[(size_t)b * Ss + i] = i - bp[src][i];
}

__device__ __forceinline__ bf16x8 lds_frag(const char* buf, int row, int cb) {
  return *(const bf16x8*)(buf + row * 128 + (cb ^ ((row & 7) << 4)));
}

// ================= 128x256 2-phase GEMM core, TRIPLE-buffered, prefetch distance 2 =================
// A [M][2048], B [N][2048]. Tile 128x256. 8 waves as 2(M) x 4(N), wave tile 64x64.
// LDS: 3 buf x (A [128][64]=16K + B [256][64]=32K) = 144 KiB.
// Slots (2 loads each): s0=A, s1=B-up, s2=B-lo. At tile t: ph0 issues s0,s1(t+2);
// ph1 issues s2(t+2). FIFO ledger (steady state 8 outstanding entering ph0):
//   ph0: +4 -> 12, vmcnt(10) retires s2(t);  ph1: +2 -> 12, vmcnt(8) retires s0,s1(t+1).
//   Issue->wait gap = 3 phases for every slot (covers L2/HBM latency).
// Prologue: stage t0,t1 (12 loads), vmcnt(8) retires t0.s0,s1.
// Tail: tile N-2: vmcnt(6)/vmcnt(2); tile N-1: vmcnt(0)/none.
__device__ __forceinline__ void stage_slot128(const bf16* gA, const bf16* gB,
                                              int m0, int n0, int t, int slot, int buf,
                                              char* AL, char* BL, int tid) {
  const char* gp; char* l; int rbase;
  char* bufA = AL + (size_t)buf * 16384;
  char* bufB = BL + (size_t)buf * 32768;
  if (slot == 0)      { gp = (const char*)gA; l = bufA;         rbase = m0; }
  else if (slot == 1) { gp = (const char*)gB; l = bufB;         rbase = n0; }
  else                { gp = (const char*)gB; l = bufB + 16384; rbase = n0 + 128; }
  int ktb = t * 128;
#pragma unroll
  for (int p = 0; p < 2; p++) {
    int o = p * 8192 + tid * 16;
    int r = o >> 7, cb = o & 127;
    gload_lds16(gp + (size_t)(rbase + r) * 4096 + ktb + (cb ^ ((r & 7) << 4)), l + o);
  }
}

template <bool STAGE, int WV0, int WV1>
__device__ __forceinline__ void do_tile128(const bf16* gA, const bf16* gB, int m0, int n0,
                                           int t, int bi, int b2, char* AL, char* BL, int tid,
                                           int wr, int wc, int ln, int g,
                                           f32x4 acc[4][4]) {
  const char* tileA = AL + (size_t)bi * 16384;
  const char* tileB = BL + (size_t)bi * 32768;
  bf16x8 af[4][2], bf_[2][2];

  // ---- phase 0: read A + B-up of t; issue s0,s1(t+2); retire s2(t) ----
#pragma unroll
  for (int mq = 0; mq < 4; mq++)
#pragma unroll
    for (int kk = 0; kk < 2; kk++)
      af[mq][kk] = lds_frag(tileA, wr * 64 + mq * 16 + ln, kk * 64 + g * 16);
#pragma unroll
  for (int nq = 0; nq < 2; nq++)
#pragma unroll
    for (int kk = 0; kk < 2; kk++)
      bf_[nq][kk] = lds_frag(tileB, wc * 32 + nq * 16 + ln, kk * 64 + g * 16);
  if (STAGE) {
    stage_slot128(gA, gB, m0, n0, t + 2, 0, b2, AL, BL, tid);
    stage_slot128(gA, gB, m0, n0, t + 2, 1, b2, AL, BL, tid);
  }
  waitv<WV0>();
  __builtin_amdgcn_s_barrier();
  __builtin_amdgcn_s_setprio(1);
#pragma unroll
  for (int mq = 0; mq < 4; mq++)
#pragma unroll
    for (int nq = 0; nq < 2; nq++)
#pragma unroll
      for (int kk = 0; kk < 2; kk++)
        acc[mq][nq] = __builtin_amdgcn_mfma_f32_16x16x32_bf16(af[mq][kk], bf_[nq][kk], acc[mq][nq], 0, 0, 0);
  __builtin_amdgcn_s_setprio(0);
  __builtin_amdgcn_s_barrier();

  // ---- phase 1: read B-lo of t; issue s2(t+2); retire s0,s1(t+1) ----
#pragma unroll
  for (int nq = 0; nq < 2; nq++)
#pragma unroll
    for (int kk = 0; kk < 2; kk++)
      bf_[nq][kk] = lds_frag(tileB, 128 + wc * 32 + nq * 16 + ln, kk * 64 + g * 16);
  if (STAGE)
    stage_slot128(gA, gB, m0, n0, t + 2, 2, b2, AL, BL, tid);
  waitv<WV1>();
  __builtin_amdgcn_s_barrier();
  __builtin_amdgcn_s_setprio(1);
#pragma unroll
  for (int mq = 0; mq < 4; mq++)
#pragma unroll
    for (int nq = 0; nq < 2; nq++)
#pragma unroll
      for (int kk = 0; kk < 2; kk++)
        acc[mq][2 + nq] = __builtin_amdgcn_mfma_f32_16x16x32_bf16(af[mq][kk], bf_[nq][kk], acc[mq][2 + nq], 0, 0, 0);
  __builtin_amdgcn_s_setprio(0);
  __builtin_amdgcn_s_barrier();
}

__device__ __forceinline__ void gemm128_core(const bf16* gA, const bf16* gB,
                                             int m0, int n0, char* AL, char* BL,
                                             f32x4 acc[4][4]) {
  const int tid = threadIdx.x;
  const int l = tid & 63, w = tid >> 6;
  const int wr = w >> 2, wc = w & 3;
  const int g = l >> 4, ln = l & 15;
  f32x4 z = {0.f, 0.f, 0.f, 0.f};
#pragma unroll
  for (int i = 0; i < 4; i++)
#pragma unroll
    for (int n = 0; n < 4; n++) acc[i][n] = z;

  // prologue: stage tiles 0 and 1 completely (12 loads); retire t0.s0,s1 (leave 8)
  stage_slot128(gA, gB, m0, n0, 0, 0, 0, AL, BL, tid);
  stage_slot128(gA, gB, m0, n0, 0, 1, 0, AL, BL, tid);
  stage_slot128(gA, gB, m0, n0, 0, 2, 0, AL, BL, tid);
  stage_slot128(gA, gB, m0, n0, 1, 0, 1, AL, BL, tid);
  stage_slot128(gA, gB, m0, n0, 1, 1, 1, AL, BL, tid);
  stage_slot128(gA, gB, m0, n0, 1, 2, 1, AL, BL, tid);
  waitv<8>();
  __builtin_amdgcn_s_barrier();

  int bi = 0, b2 = 2;
  for (int t = 0; t < NTILES - 2; t++) {
    do_tile128<true, 10, 8>(gA, gB, m0, n0, t, bi, b2, AL, BL, tid, wr, wc, ln, g, acc);
    bi = (bi == 2) ? 0 : bi + 1;
    b2 = (b2 == 2) ? 0 : b2 + 1;
  }
  do_tile128<false, 6, 2>(gA, gB, m0, n0, NTILES - 2, bi, 0, AL, BL, tid, wr, wc, ln, g, acc);
  bi = (bi == 2) ? 0 : bi + 1;
  do_tile128<false, 0, -1>(gA, gB, m0, n0, NTILES - 1, bi, 0, AL, BL, tid, wr, wc, ln, g, acc);
}

// ------------- fused QKV projection + RoPE epilogue (128x256 tiles, 768 blocks = 3 exact rounds) -------------
// gB = wqkvt [6144][2048]; cols 0-2047 -> Q, 2048-4095 -> K, 4096-6143 -> V.
// Q,K out: [B][H][S][HD] (LDS-transpose epilogue in 2 passes of 64 rows, in-register RoPE pairs).
// V out: DIRECT transposed [B][H][HD][S] bf16x4 stores (r2-quad = 4 consecutive s).
__global__ __launch_bounds__(512, 2) void k_qkv128(const bf16* __restrict__ xb,
                                                   const bf16* __restrict__ wqkvt,
                                                   const int* __restrict__ pos,
                                                   bf16* __restrict__ q,
                                                   bf16* __restrict__ k,
                                                   bf16* __restrict__ vt) {
  __shared__ char SLM[147456];  // GEMM: A 3x16K + B 3x32K; epilogue: 64x260 f32 view (65 KB)
  char* AL = SLM;
  char* BL = SLM + 49152;
  int bid = blockIdx.x;                    // 768 blocks
  int idx = (bid & 7) * 96 + (bid >> 3);   // XCD swizzle (768 % 8 == 0)
  int mt = idx / 24, nt = idx % 24;        // same-XCD neighbors share mt -> A-panel L2 reuse
  int m0 = mt * 128, n0 = nt * 256;

  f32x4 acc[4][4];
  gemm128_core(xb, wqkvt, m0, n0, AL, BL, acc);

  const int tid = threadIdx.x;
  const int l = tid & 63, w = tid >> 6;
  const int wr = w >> 2, wc = w & 3, g = l >> 4, ln = l & 15;
  int z = n0 >> 11;                         // 0=Q 1=K 2=V (block-uniform)
  int n0l = n0 & 2047;
  int bix = m0 >> 11;
  int sl0 = m0 & 2047;                      // 128-row tile never crosses batch boundary

  if (z == 2) {
    // V: straight from acc, transposed layout [B][H][HD][S], 8 B stores
#pragma unroll
    for (int mq = 0; mq < 4; mq++) {
      int sl = sl0 + wr * 64 + mq * 16 + g * 4;
#pragma unroll
      for (int ni = 0; ni < 4; ni++) {
        int col = n0l + (ni >> 1) * 128 + wc * 32 + (ni & 1) * 16 + ln;
        int h = col >> 7, hd = col & 127;
        bf16x4 o;
#pragma unroll
        for (int r2 = 0; r2 < 4; r2++) o[r2] = (bf16)acc[mq][ni][r2];
        *(bf16x4*)(vt + (((size_t)(bix * Hh + h) * HDd + hd) * Ss + sl)) = o;
      }
    }
  } else {
    bf16* dst = (z == 0) ? q : k;
    float* T = (float*)SLM;                 // stride 260 floats, 64 rows per pass (65 KB < 144 KiB)
    const float c1 = 0.14391156642398168f;  // ln(10000)/64
    int cg = (tid & 31) * 8;                // per-thread column base (8 consecutive cols)
    int hb = n0l + cg;
    int hh = hb >> 7, hd0 = hb & 127;       // constant per thread
    float fr[4];
#pragma unroll
    for (int pr = 0; pr < 4; pr++)
      fr[pr] = __expf(-(float)((hd0 >> 1) + pr) * c1);

#pragma unroll
    for (int pass = 0; pass < 2; pass++) {
      __syncthreads();
      // scatter 64 rows of acc into LDS (waves with wr==pass own these rows)
      if (wr == pass) {
#pragma unroll
        for (int mq = 0; mq < 4; mq++) {
#pragma unroll
          for (int ni = 0; ni < 4; ni++) {
            int c = (ni >> 1) * 128 + wc * 32 + (ni & 1) * 16 + ln;
            int rb = mq * 16 + g * 4;
#pragma unroll
            for (int r2 = 0; r2 < 4; r2++)
              T[(rb + r2) * 260 + c] = acc[mq][ni][r2];
          }
        }
      }
      __syncthreads();
      // gather rows: 8 consecutive hd per thread, RoPE pairs in-register, 16 B stores
#pragma unroll
      for (int j = 0; j < 4; j++) {
        int r = j * 16 + (tid >> 5);
        int sg = m0 + pass * 64 + r;
        float p = (float)pos[sg];
        f32x4 v0 = *(const f32x4*)(T + r * 260 + cg);
        f32x4 v1 = *(const f32x4*)(T + r * 260 + cg + 4);
        float e0[4] = {v0[0], v0[2], v1[0], v1[2]};
        float e1[4] = {v0[1], v0[3], v1[1], v1[3]};
        int s = sg & 2047;
        bf16x8 o;
#pragma unroll
        for (int pr = 0; pr < 4; pr++) {
          float ang = p * fr[pr];
          float sn, cs;
          __sincosf(ang, &sn, &cs);
          o[2 * pr]     = (bf16)(e0[pr] * cs - e1[pr] * sn);
          o[2 * pr + 1] = (bf16)(e1[pr] * cs + e0[pr] * sn);
        }
        *(bf16x8*)(dst + (((size_t)(bix * Hh + hh) * Ss + s) * HDd + hd0)) = o;
      }
    }
  }
}

// ------------- final projection + bias (fp32 out), 128x256 tiles, 256 blocks = full GPU -------------
__global__ __launch_bounds__(512, 2) void k_out128(const bf16* __restrict__ ctx,
                                                   const bf16* __restrict__ wot,
                                                   const float* __restrict__ bo,
                                                   float* __restrict__ outp) {
  __shared__ char AL[49152];
  __shared__ char BL[98304];
  int bid = blockIdx.x;                    // 256 blocks
  int x = bid & 7, j = bid >> 3;           // XCD x gets an 8(mt) x 4(nt) chunk
  int mt = (x >> 1) * 8 + (j >> 2);
  int nt = (x & 1) * 4 + (j & 3);
  int m0 = mt * 128, n0 = nt * 256;

  f32x4 acc[4][4];
  gemm128_core(ctx, wot, m0, n0, AL, BL, acc);

  const int l = threadIdx.x & 63, w = threadIdx.x >> 6;
  const int wr = w >> 2, wc = w & 3, g = l >> 4, ln = l & 15;
  float bov[4];
#pragma unroll
  for (int ni = 0; ni < 4; ni++)
    bov[ni] = bo[n0 + (ni >> 1) * 128 + wc * 32 + (ni & 1) * 16 + ln];
#pragma unroll
  for (int mq = 0; mq < 4; mq++)
#pragma unroll
    for (int r2 = 0; r2 < 4; r2++) {
      int row = m0 + wr * 64 + mq * 16 + g * 4 + r2;
#pragma unroll
      for (int ni = 0; ni < 4; ni++) {
        int col = n0 + (ni >> 1) * 128 + wc * 32 + (ni & 1) * 16 + ln;
        outp[(size_t)row * Dd + col] = acc[mq][ni][r2] + bov[ni];
      }
    }
}

// ------------- flash attention with doc+causal mask -------------
__global__ __launch_bounds__(256) void k_attn(const bf16* __restrict__ q,
                                              const bf16* __restrict__ k,
                                              const bf16* __restrict__ vt,
                                              const int* __restrict__ pos,
                                              bf16* __restrict__ ctx) {
  __shared__ bf16 Ks[64 * 128];    // K tile  [kv][hd]
  __shared__ bf16 Vts[128 * 64];   // Vt tile [hd][kv]
  __shared__ bf16 Pw[4][16 * 64];  // per-wave P [qrow][kv]
  int bh = blockIdx.y;
  int b = bh >> 4, h = bh & 15;
  int qt = blockIdx.x, q0 = qt * 64;
  const int tid = threadIdx.x, l = tid & 63, w = tid >> 6, g = l >> 4, ln = l & 15;
  const bf16* qb = q + (size_t)bh * Ss * HDd;
  const bf16* kb = k + (size_t)bh * Ss * HDd;
  const bf16* vb = vt + (size_t)bh * Ss * HDd;

  bf16x8 qf[4];
  int qr = q0 + w * 16 + ln;
#pragma unroll
  for (int ks = 0; ks < 4; ks++)
    qf[ks] = *(const bf16x8*)(qb + (size_t)qr * HDd + ks * 32 + 8 * g);

  int rrow[4], dstart[4];
  float m[4], lsum[4];
#pragma unroll
  for (int r2 = 0; r2 < 4; r2++) {
    rrow[r2] = q0 + w * 16 + 4 * g + r2;
    dstart[r2] = rrow[r2] - pos[(size_t)b * Ss + rrow[r2]];
    m[r2] = -1e30f;
    lsum[r2] = 0.f;
  }
  f32x4 oacc[8];
  f32x4 z = {0.f, 0.f, 0.f, 0.f};
#pragma unroll
  for (int n = 0; n < 8; n++) oacc[n] = z;

  int kt_start = (q0 - pos[(size_t)b * Ss + q0]) >> 6;
  const float iscale = 0.08838834764831845f;  // 1/sqrt(128)

  for (int kt = kt_start; kt <= qt; kt++) {
    int kv0 = kt * 64;
#pragma unroll
    for (int i2 = 0; i2 < 4; i2++) {
      int o = i2 * 4096 + w * 1024 + l * 16;
      int rk = o >> 8, cbk = o & 255;
      gload_lds16((const char*)kb + (size_t)(kv0 + rk) * 256 + cbk,
                  (char*)Ks + i2 * 4096 + w * 1024);
      int rv = o >> 7, cbv = o & 127;
      gload_lds16((const char*)vb + (size_t)rv * (Ss * 2) + (size_t)kv0 * 2 + cbv,
                  (char*)Vts + i2 * 4096 + w * 1024);
    }
    __syncthreads();

    f32x4 sc[4];
#pragma unroll
    for (int n = 0; n < 4; n++) {
      f32x4 a = z;
#pragma unroll
      for (int ks = 0; ks < 4; ks++) {
        bf16x8 bfrag = *(const bf16x8*)(Ks + (n * 16 + ln) * 128 + ks * 32 + 8 * g);
        a = __builtin_amdgcn_mfma_f32_16x16x32_bf16(qf[ks], bfrag, a, 0, 0, 0);
      }
      sc[n] = a;
    }

    float pmax[4] = {-1e30f, -1e30f, -1e30f, -1e30f};
    float pv[4][4];
#pragma unroll
    for (int n = 0; n < 4; n++) {
      int kvc = kv0 + n * 16 + ln;
#pragma unroll
      for (int r2 = 0; r2 < 4; r2++) {
        bool ok = (kvc <= rrow[r2]) && (kvc >= dstart[r2]);
        float sv = ok ? sc[n][r2] * iscale : -1e30f;
        pv[n][r2] = sv;
        pmax[r2] = fmaxf(pmax[r2], sv);
      }
    }
#pragma unroll
    for (int off = 1; off < 16; off <<= 1)
#pragma unroll
      for (int r2 = 0; r2 < 4; r2++)
        pmax[r2] = fmaxf(pmax[r2], __shfl_xor(pmax[r2], off, 64));

    float alpha[4];
#pragma unroll
    for (int r2 = 0; r2 < 4; r2++) {
      float mn = fmaxf(m[r2], pmax[r2]);
      alpha[r2] = __expf(m[r2] - mn);
      m[r2] = mn;
    }

    float rs[4] = {0.f, 0.f, 0.f, 0.f};
#pragma unroll
    for (int n = 0; n < 4; n++) {
      int kvc = kv0 + n * 16 + ln;
#pragma unroll
      for (int r2 = 0; r2 < 4; r2++) {
        bool ok = (kvc <= rrow[r2]) && (kvc >= dstart[r2]);
        float p = ok ? __expf(pv[n][r2] - m[r2]) : 0.f;
        rs[r2] += p;
        Pw[w][(4 * g + r2) * 64 + n * 16 + ln] = (bf16)p;
      }
    }
#pragma unroll
    for (int off = 1; off < 16; off <<= 1)
#pragma unroll
      for (int r2 = 0; r2 < 4; r2++) rs[r2] += __shfl_xor(rs[r2], off, 64);
#pragma unroll
    for (int r2 = 0; r2 < 4; r2++) lsum[r2] = lsum[r2] * alpha[r2] + rs[r2];
#pragma unroll
    for (int n = 0; n < 8; n++)
#pragma unroll
      for (int r2 = 0; r2 < 4; r2++) oacc[n][r2] *= alpha[r2];
    __syncthreads();

#pragma unroll
    for (int n = 0; n < 8; n++) {
#pragma unroll
      for (int ks = 0; ks < 2; ks++) {
        bf16x8 pa = *(const bf16x8*)(&Pw[w][ln * 64 + ks * 32 + 8 * g]);
        bf16x8 vfr = *(const bf16x8*)(Vts + (n * 16 + ln) * 64 + ks * 32 + 8 * g);
        oacc[n] = __builtin_amdgcn_mfma_f32_16x16x32_bf16(pa, vfr, oacc[n], 0, 0, 0);
      }
    }
    __syncthreads();
  }

#pragma unroll
  for (int n = 0; n < 8; n++)
#pragma unroll
    for (int r2 = 0; r2 < 4; r2++) {
      float val = oacc[n][r2] / lsum[r2];
      ctx[((size_t)(b * Ss + rrow[r2])) * Dd + h * HDd + n * 16 + ln] = (bf16)val;
    }
}

extern "C" void kernel_launch(void* const* d_in, const int* in_sizes, int n_in,
                              void* d_out, int out_size, void* d_ws, size_t ws_size,
                              hipStream_t stream) {
  const float* x = (const float*)d_in[0];
  const int* doc = (const int*)d_in[1];
  const float* Wq = (const float*)d_in[2];
  const float* Wk = (const float*)d_in[3];
  const float* Wv = (const float*)d_in[4];
  const float* Wo = (const float*)d_in[5];
  const float* bo = (const float*)d_in[6];
  float* outp = (float*)d_out;

  char* ws = (char*)d_ws;
  size_t off = 0;
  auto alloc = [&](size_t bytes) {
    char* p = ws + off;
    off += (bytes + 255) & ~(size_t)255;
    return p;
  };
  bf16* xb = (bf16*)alloc((size_t)BSs * Dd * 2);
  bf16* wqkvt = (bf16*)alloc((size_t)3 * Dd * Dd * 2);  // [6144][2048]
  bf16* wot = (bf16*)alloc((size_t)Dd * Dd * 2);
  bf16* qd = (bf16*)alloc((size_t)BSs * Dd * 2);
  bf16* kd = (bf16*)alloc((size_t)BSs * Dd * 2);
  bf16* vtd = (bf16*)alloc((size_t)BSs * Dd * 2);  // V stored transposed directly
  bf16* ctxd = (bf16*)alloc((size_t)BSs * Dd * 2);
  int* pos = (int*)alloc((size_t)BSs * 4);

  k_cvtx<<<(BSs * Dd) / 1024, 256, 0, stream>>>(x, xb);
  k_tw<<<dim3(Dd / 64, Dd / 64, 4), 256, 0, stream>>>(
      Wq, Wk, Wv, Wo, wqkvt, wqkvt + (size_t)Dd * Dd, wqkvt + (size_t)2 * Dd * Dd, wot);
  k_pos<<<Bb, 1024, 0, stream>>>(doc, pos);
  k_qkv128<<<dim3(768), 512, 0, stream>>>(xb, wqkvt, pos, qd, kd, vtd);
  k_attn<<<dim3(Ss / 64, Bb * Hh), 256, 0, stream>>>(qd, kd, vtd, pos, ctxd);
  k_out128<<<dim3(256), 512, 0, stream>>>(ctxd, wot, bo, outp);
}